// Round 1
// baseline (554.339 us; speedup 1.0000x reference)
//
#include <hip/hip_runtime.h>
#include <hip/hip_bf16.h>

// Problem constants (from reference)
#define B_SZ   2
#define N_IN   163842
#define N_OUT  40962
#define C_DIM  128
#define K_CAND 7
// 1/(2*SIGMA^2), SIGMA=0.4
#define INV_2SIG2 3.125f

// Phase 1: scatter-add weighted x into down, omega into denom.
// grid.x = N_IN, block = 128 (one thread per channel)
__global__ __launch_bounds__(C_DIM) void scatter_kernel(
    const float* __restrict__ x,        // (B, N_IN, C)
    const float* __restrict__ omega,    // (N_IN,)
    const int*   __restrict__ parent,   // (N_IN,)
    float* __restrict__ down,           // (B, N_OUT, C)
    float* __restrict__ denom)          // (N_OUT,)
{
    const int n = blockIdx.x;
    const int c = threadIdx.x;
    const int p = parent[n];
    const float om = omega[n];

    if (c == 0) {
        atomicAdd(&denom[p], om);
    }

    // b = 0
    atomicAdd(&down[(size_t)p * C_DIM + c],
              x[(size_t)n * C_DIM + c] * om);
    // b = 1
    atomicAdd(&down[((size_t)N_OUT + p) * C_DIM + c],
              x[((size_t)N_IN + n) * C_DIM + c] * om);
}

// Phase 2: per-n candidate weights + gather + weighted sum.
// grid = (N_IN, B), block = 128 (one thread per channel)
__global__ __launch_bounds__(C_DIM) void gather_kernel(
    const float* __restrict__ delta,     // (N_IN, K)
    const float* __restrict__ cand_mask, // (N_IN, K)
    const int*   __restrict__ cand_idx,  // (N_IN, K)
    const float* __restrict__ down,      // (B, N_OUT, C)  (UN-normalized)
    const float* __restrict__ denom,     // (N_OUT,)
    float* __restrict__ out)             // (B, N_IN, C)
{
    const int n = blockIdx.x;
    const int b = blockIdx.y;
    const int c = threadIdx.x;

    __shared__ float w_sh[K_CAND];
    __shared__ float coef_sh[K_CAND];
    __shared__ int   idx_sh[K_CAND];

    if (c < K_CAND) {
        const float d = delta[(size_t)n * K_CAND + c];
        w_sh[c] = __expf(-d * d * INV_2SIG2) * cand_mask[(size_t)n * K_CAND + c];
        idx_sh[c] = cand_idx[(size_t)n * K_CAND + c];
    }
    __syncthreads();
    if (c < K_CAND) {
        float s = 0.f;
        #pragma unroll
        for (int k = 0; k < K_CAND; ++k) s += w_sh[k];
        s = fmaxf(s, 1e-8f);
        const float dn = fmaxf(denom[idx_sh[c]], 1e-8f);
        // fold the scatter-mean division into the gather coefficient
        coef_sh[c] = w_sh[c] / (s * dn);
    }
    __syncthreads();

    const float* dbase = down + (size_t)b * N_OUT * C_DIM;
    float acc = 0.f;
    #pragma unroll
    for (int k = 0; k < K_CAND; ++k) {
        acc += coef_sh[k] * dbase[(size_t)idx_sh[k] * C_DIM + c];
    }
    out[((size_t)b * N_IN + n) * C_DIM + c] = acc;
}

extern "C" void kernel_launch(void* const* d_in, const int* in_sizes, int n_in,
                              void* d_out, int out_size, void* d_ws, size_t ws_size,
                              hipStream_t stream) {
    const float* x         = (const float*)d_in[0];
    const float* omega     = (const float*)d_in[1];
    const float* delta     = (const float*)d_in[2];
    const float* cand_mask = (const float*)d_in[3];
    const int*   parent    = (const int*)d_in[4];
    const int*   cand_idx  = (const int*)d_in[5];
    float* out = (float*)d_out;

    // workspace layout: down (B*N_OUT*C floats) | denom (N_OUT floats)
    float* down  = (float*)d_ws;
    float* denom = down + (size_t)B_SZ * N_OUT * C_DIM;
    const size_t ws_floats = (size_t)B_SZ * N_OUT * C_DIM + N_OUT;

    hipMemsetAsync(d_ws, 0, ws_floats * sizeof(float), stream);

    scatter_kernel<<<dim3(N_IN), dim3(C_DIM), 0, stream>>>(
        x, omega, parent, down, denom);

    gather_kernel<<<dim3(N_IN, B_SZ), dim3(C_DIM), 0, stream>>>(
        delta, cand_mask, cand_idx, down, denom, out);
}

// Round 2
// 469.837 us; speedup vs baseline: 1.1799x; 1.1799x over previous
//
#include <hip/hip_runtime.h>
#include <hip/hip_bf16.h>

// Problem constants (from reference)
#define B_SZ   2
#define N_IN   163842
#define N_OUT  40962
#define C_DIM  128
#define K_CAND 7
// 1/(2*SIGMA^2), SIGMA=0.4
#define INV_2SIG2 3.125f

// ---------- Pass A: count children per parent ----------
__global__ __launch_bounds__(256) void count_kernel(
    const int* __restrict__ parent, int* __restrict__ count)
{
    int n = blockIdx.x * 256 + threadIdx.x;
    if (n < N_IN) atomicAdd(&count[parent[n]], 1);
}

// ---------- Pass B: exclusive prefix sum over counts (single block) ----------
__global__ __launch_bounds__(1024) void scan_kernel(
    const int* __restrict__ count, int* __restrict__ offs)
{
    __shared__ int part[1024];
    const int CH = (N_OUT + 1023) / 1024;  // 41
    const int t = threadIdx.x;
    const int start = t * CH;

    int s = 0;
    for (int i = 0; i < CH; ++i) {
        int j = start + i;
        if (j < N_OUT) s += count[j];
    }
    part[t] = s;
    __syncthreads();

    // Hillis-Steele inclusive scan (read-before-write guaranteed by barriers)
    for (int off = 1; off < 1024; off <<= 1) {
        int v = (t >= off) ? part[t - off] : 0;
        __syncthreads();
        part[t] += v;
        __syncthreads();
    }

    int run = (t == 0) ? 0 : part[t - 1];  // exclusive base for this chunk
    for (int i = 0; i < CH; ++i) {
        int j = start + i;
        if (j < N_OUT) { offs[j] = run; run += count[j]; }
    }
}

// ---------- Pass C: fill permutation (CSR child lists) ----------
__global__ __launch_bounds__(256) void fill_kernel(
    const int* __restrict__ parent, const int* __restrict__ offs,
    int* __restrict__ cursor, int* __restrict__ perm)
{
    int n = blockIdx.x * 256 + threadIdx.x;
    if (n < N_IN) {
        int p = parent[n];
        int pos = offs[p] + atomicAdd(&cursor[p], 1);
        perm[pos] = n;
    }
}

// ---------- Pass D: per-parent reduce, normalize, store bf16 ----------
// grid = N_OUT, block = 128 (one thread per channel)
__global__ __launch_bounds__(C_DIM) void reduce_kernel(
    const float* __restrict__ x,       // (B, N_IN, C)
    const float* __restrict__ omega,   // (N_IN,)
    const int*   __restrict__ offs,
    const int*   __restrict__ perm,
    __hip_bfloat16* __restrict__ down) // (B, N_OUT, C) normalized
{
    const int p = blockIdx.x;
    const int c = threadIdx.x;
    const int beg = offs[p];
    const int end = (p + 1 < N_OUT) ? offs[p + 1] : N_IN;

    float a0 = 0.f, a1 = 0.f, ds = 0.f;
    for (int i = beg; i < end; ++i) {
        const int n = perm[i];            // broadcast load
        const float om = omega[n];        // broadcast load
        ds += om;
        a0 = fmaf(x[(size_t)n * C_DIM + c], om, a0);
        a1 = fmaf(x[((size_t)N_IN + n) * C_DIM + c], om, a1);
    }
    const float inv = 1.f / fmaxf(ds, 1e-8f);
    down[(size_t)p * C_DIM + c]                 = __float2bfloat16(a0 * inv);
    down[((size_t)N_OUT + p) * C_DIM + c]       = __float2bfloat16(a1 * inv);
}

// ---------- Pass E: weighted gather ----------
// 4 groups of 64 lanes per block; each group handles one n (both b).
// Each lane loads __hip_bfloat162 (2 channels).
__global__ __launch_bounds__(256) void gather_kernel(
    const float* __restrict__ delta,     // (N_IN, K)
    const float* __restrict__ cand_mask, // (N_IN, K)
    const int*   __restrict__ cand_idx,  // (N_IN, K)
    const __hip_bfloat16* __restrict__ down, // (B, N_OUT, C) normalized
    float* __restrict__ out)             // (B, N_IN, C)
{
    const int g    = threadIdx.x >> 6;   // 0..3
    const int lane = threadIdx.x & 63;
    const int n    = blockIdx.x * 4 + g;

    __shared__ float w_sh[4][8];
    __shared__ float coef_sh[4][8];
    __shared__ int   idx_sh[4][8];

    if (n < N_IN && lane < K_CAND) {
        const float d = delta[(size_t)n * K_CAND + lane];
        w_sh[g][lane] = __expf(-d * d * INV_2SIG2) *
                        cand_mask[(size_t)n * K_CAND + lane];
        idx_sh[g][lane] = cand_idx[(size_t)n * K_CAND + lane];
    }
    __syncthreads();
    if (n < N_IN && lane < K_CAND) {
        float s = 0.f;
        #pragma unroll
        for (int k = 0; k < K_CAND; ++k) s += w_sh[g][k];
        coef_sh[g][lane] = w_sh[g][lane] / fmaxf(s, 1e-8f);
    }
    __syncthreads();

    if (n >= N_IN) return;

    const __hip_bfloat162* d2 = (const __hip_bfloat162*)down;
    float2 acc0 = make_float2(0.f, 0.f);
    float2 acc1 = make_float2(0.f, 0.f);
    #pragma unroll
    for (int k = 0; k < K_CAND; ++k) {
        const float cf = coef_sh[g][k];
        const int   p  = idx_sh[g][k];
        const __hip_bfloat162 v0 = d2[(size_t)p * 64 + lane];
        const __hip_bfloat162 v1 = d2[((size_t)N_OUT + p) * 64 + lane];
        acc0.x = fmaf(cf, __bfloat162float(v0.x), acc0.x);
        acc0.y = fmaf(cf, __bfloat162float(v0.y), acc0.y);
        acc1.x = fmaf(cf, __bfloat162float(v1.x), acc1.x);
        acc1.y = fmaf(cf, __bfloat162float(v1.y), acc1.y);
    }
    float2* o2 = (float2*)out;
    o2[(size_t)n * 64 + lane]                 = acc0;
    o2[((size_t)N_IN + n) * 64 + lane]        = acc1;
}

extern "C" void kernel_launch(void* const* d_in, const int* in_sizes, int n_in,
                              void* d_out, int out_size, void* d_ws, size_t ws_size,
                              hipStream_t stream) {
    const float* x         = (const float*)d_in[0];
    const float* omega     = (const float*)d_in[1];
    const float* delta     = (const float*)d_in[2];
    const float* cand_mask = (const float*)d_in[3];
    const int*   parent    = (const int*)d_in[4];
    const int*   cand_idx  = (const int*)d_in[5];
    float* out = (float*)d_out;

    // workspace: down bf16 (B*N_OUT*C) | count | cursor | offs | perm
    __hip_bfloat16* down = (__hip_bfloat16*)d_ws;
    int* ints   = (int*)(down + (size_t)B_SZ * N_OUT * C_DIM);
    int* count  = ints;
    int* cursor = ints + N_OUT;
    int* offs   = ints + 2 * N_OUT;
    int* perm   = ints + 3 * N_OUT;

    // zero count + cursor only (328 KB)
    hipMemsetAsync(ints, 0, (size_t)2 * N_OUT * sizeof(int), stream);

    const int nblk = (N_IN + 255) / 256;
    count_kernel<<<nblk, 256, 0, stream>>>(parent, count);
    scan_kernel<<<1, 1024, 0, stream>>>(count, offs);
    fill_kernel<<<nblk, 256, 0, stream>>>(parent, offs, cursor, perm);
    reduce_kernel<<<N_OUT, C_DIM, 0, stream>>>(x, omega, offs, perm, down);
    gather_kernel<<<(N_IN + 3) / 4, 256, 0, stream>>>(
        delta, cand_mask, cand_idx, down, out);
}

// Round 3
// 417.172 us; speedup vs baseline: 1.3288x; 1.1262x over previous
//
#include <hip/hip_runtime.h>
#include <hip/hip_bf16.h>

// Problem constants (from reference)
#define B_SZ   2
#define N_IN   163842
#define N_OUT  40962
#define C_DIM  128
#define K_CAND 7
// 1/(2*SIGMA^2), SIGMA=0.4
#define INV_2SIG2 3.125f

#define SCAN_B 256
#define NBLK_SCAN ((N_OUT + SCAN_B - 1) / SCAN_B)   // 161

// ---------- Pass A: count children per parent ----------
__global__ __launch_bounds__(256) void count_kernel(
    const int* __restrict__ parent, int* __restrict__ count)
{
    int n = blockIdx.x * 256 + threadIdx.x;
    if (n < N_IN) atomicAdd(&count[parent[n]], 1);
}

// ---------- Pass B1: per-block exclusive scan (coalesced) ----------
__global__ __launch_bounds__(SCAN_B) void scan1_kernel(
    const int* __restrict__ count, int* __restrict__ offs, int* __restrict__ bsum)
{
    __shared__ int sh[SCAN_B];
    const int t = threadIdx.x;
    const int j = blockIdx.x * SCAN_B + t;
    const int c = (j < N_OUT) ? count[j] : 0;
    sh[t] = c;
    __syncthreads();
    for (int off = 1; off < SCAN_B; off <<= 1) {
        int v = (t >= off) ? sh[t - off] : 0;
        __syncthreads();
        sh[t] += v;
        __syncthreads();
    }
    if (j < N_OUT) offs[j] = sh[t] - c;              // exclusive within block
    if (t == SCAN_B - 1) bsum[blockIdx.x] = sh[t];   // block total
}

// ---------- Pass B2: scan the 161 block sums (single small block) ----------
__global__ __launch_bounds__(SCAN_B) void scan2_kernel(
    const int* __restrict__ bsum, int* __restrict__ bbase)
{
    __shared__ int sh[SCAN_B];
    const int t = threadIdx.x;
    const int s = (t < NBLK_SCAN) ? bsum[t] : 0;
    sh[t] = s;
    __syncthreads();
    for (int off = 1; off < SCAN_B; off <<= 1) {
        int v = (t >= off) ? sh[t - off] : 0;
        __syncthreads();
        sh[t] += v;
        __syncthreads();
    }
    if (t < NBLK_SCAN) bbase[t] = sh[t] - s;         // exclusive block base
}

// ---------- Pass B3: add block bases ----------
__global__ __launch_bounds__(SCAN_B) void scan3_kernel(
    int* __restrict__ offs, const int* __restrict__ bbase)
{
    const int j = blockIdx.x * SCAN_B + threadIdx.x;
    if (j < N_OUT && blockIdx.x > 0) offs[j] += bbase[blockIdx.x];
}

// ---------- Pass C: fill permutation (CSR child lists) ----------
__global__ __launch_bounds__(256) void fill_kernel(
    const int* __restrict__ parent, const int* __restrict__ offs,
    int* __restrict__ cursor, int* __restrict__ perm)
{
    int n = blockIdx.x * 256 + threadIdx.x;
    if (n < N_IN) {
        int p = parent[n];
        int pos = offs[p] + atomicAdd(&cursor[p], 1);
        perm[pos] = n;
    }
}

// ---------- Pass D: per-parent reduce, normalize, store bf16 ----------
// 256 threads = 8 parents x 32 lanes; each lane owns 4 channels (float4),
// accumulates both batch copies.
__global__ __launch_bounds__(256) void reduce_kernel(
    const float* __restrict__ x,       // (B, N_IN, C)
    const float* __restrict__ omega,   // (N_IN,)
    const int*   __restrict__ offs,
    const int*   __restrict__ perm,
    __hip_bfloat16* __restrict__ down) // (B, N_OUT, C) normalized
{
    const int sub = threadIdx.x >> 5;            // 0..7
    const int l   = threadIdx.x & 31;            // channel group
    const int p   = blockIdx.x * 8 + sub;
    if (p >= N_OUT) return;

    const int beg = offs[p];
    const int end = (p + 1 < N_OUT) ? offs[p + 1] : N_IN;

    const float4* x4 = (const float4*)x;
    float4 a0 = make_float4(0.f, 0.f, 0.f, 0.f);
    float4 a1 = make_float4(0.f, 0.f, 0.f, 0.f);
    float ds = 0.f;

    for (int i = beg; i < end; ++i) {
        const int n = perm[i];
        const float om = omega[n];
        ds += om;
        const float4 v0 = x4[(size_t)n * 32 + l];
        const float4 v1 = x4[((size_t)N_IN + n) * 32 + l];
        a0.x = fmaf(v0.x, om, a0.x); a0.y = fmaf(v0.y, om, a0.y);
        a0.z = fmaf(v0.z, om, a0.z); a0.w = fmaf(v0.w, om, a0.w);
        a1.x = fmaf(v1.x, om, a1.x); a1.y = fmaf(v1.y, om, a1.y);
        a1.z = fmaf(v1.z, om, a1.z); a1.w = fmaf(v1.w, om, a1.w);
    }
    const float inv = 1.f / fmaxf(ds, 1e-8f);

    __hip_bfloat162* d2 = (__hip_bfloat162*)down;
    __hip_bfloat162 h;
    h.x = __float2bfloat16(a0.x * inv); h.y = __float2bfloat16(a0.y * inv);
    d2[(size_t)p * 64 + l * 2] = h;
    h.x = __float2bfloat16(a0.z * inv); h.y = __float2bfloat16(a0.w * inv);
    d2[(size_t)p * 64 + l * 2 + 1] = h;
    h.x = __float2bfloat16(a1.x * inv); h.y = __float2bfloat16(a1.y * inv);
    d2[((size_t)N_OUT + p) * 64 + l * 2] = h;
    h.x = __float2bfloat16(a1.z * inv); h.y = __float2bfloat16(a1.w * inv);
    d2[((size_t)N_OUT + p) * 64 + l * 2 + 1] = h;
}

// ---------- Pass E: weighted gather ----------
// 4 groups of 64 lanes per block; each group handles one n (both b).
__global__ __launch_bounds__(256) void gather_kernel(
    const float* __restrict__ delta,     // (N_IN, K)
    const float* __restrict__ cand_mask, // (N_IN, K)
    const int*   __restrict__ cand_idx,  // (N_IN, K)
    const __hip_bfloat16* __restrict__ down, // (B, N_OUT, C) normalized
    float* __restrict__ out)             // (B, N_IN, C)
{
    const int g    = threadIdx.x >> 6;   // 0..3
    const int lane = threadIdx.x & 63;
    const int n    = blockIdx.x * 4 + g;

    __shared__ float w_sh[4][8];
    __shared__ float coef_sh[4][8];
    __shared__ int   idx_sh[4][8];

    if (n < N_IN && lane < K_CAND) {
        const float d = delta[(size_t)n * K_CAND + lane];
        w_sh[g][lane] = __expf(-d * d * INV_2SIG2) *
                        cand_mask[(size_t)n * K_CAND + lane];
        idx_sh[g][lane] = cand_idx[(size_t)n * K_CAND + lane];
    }
    __syncthreads();
    if (n < N_IN && lane < K_CAND) {
        float s = 0.f;
        #pragma unroll
        for (int k = 0; k < K_CAND; ++k) s += w_sh[g][k];
        coef_sh[g][lane] = w_sh[g][lane] / fmaxf(s, 1e-8f);
    }
    __syncthreads();

    if (n >= N_IN) return;

    const __hip_bfloat162* d2 = (const __hip_bfloat162*)down;
    float2 acc0 = make_float2(0.f, 0.f);
    float2 acc1 = make_float2(0.f, 0.f);
    #pragma unroll
    for (int k = 0; k < K_CAND; ++k) {
        const float cf = coef_sh[g][k];
        const int   p  = idx_sh[g][k];
        const __hip_bfloat162 v0 = d2[(size_t)p * 64 + lane];
        const __hip_bfloat162 v1 = d2[((size_t)N_OUT + p) * 64 + lane];
        acc0.x = fmaf(cf, __bfloat162float(v0.x), acc0.x);
        acc0.y = fmaf(cf, __bfloat162float(v0.y), acc0.y);
        acc1.x = fmaf(cf, __bfloat162float(v1.x), acc1.x);
        acc1.y = fmaf(cf, __bfloat162float(v1.y), acc1.y);
    }
    float2* o2 = (float2*)out;
    o2[(size_t)n * 64 + lane]          = acc0;
    o2[((size_t)N_IN + n) * 64 + lane] = acc1;
}

extern "C" void kernel_launch(void* const* d_in, const int* in_sizes, int n_in,
                              void* d_out, int out_size, void* d_ws, size_t ws_size,
                              hipStream_t stream) {
    const float* x         = (const float*)d_in[0];
    const float* omega     = (const float*)d_in[1];
    const float* delta     = (const float*)d_in[2];
    const float* cand_mask = (const float*)d_in[3];
    const int*   parent    = (const int*)d_in[4];
    const int*   cand_idx  = (const int*)d_in[5];
    float* out = (float*)d_out;

    // workspace: down bf16 | count | cursor | offs | perm | bsum | bbase
    __hip_bfloat16* down = (__hip_bfloat16*)d_ws;
    int* ints   = (int*)(down + (size_t)B_SZ * N_OUT * C_DIM);
    int* count  = ints;
    int* cursor = ints + N_OUT;
    int* offs   = ints + 2 * N_OUT;
    int* perm   = ints + 3 * N_OUT;
    int* bsum   = perm + N_IN;
    int* bbase  = bsum + 256;

    // zero count + cursor only (328 KB)
    hipMemsetAsync(ints, 0, (size_t)2 * N_OUT * sizeof(int), stream);

    const int nblk = (N_IN + 255) / 256;
    count_kernel<<<nblk, 256, 0, stream>>>(parent, count);
    scan1_kernel<<<NBLK_SCAN, SCAN_B, 0, stream>>>(count, offs, bsum);
    scan2_kernel<<<1, SCAN_B, 0, stream>>>(bsum, bbase);
    scan3_kernel<<<NBLK_SCAN, SCAN_B, 0, stream>>>(offs, bbase);
    fill_kernel<<<nblk, 256, 0, stream>>>(parent, offs, cursor, perm);
    reduce_kernel<<<(N_OUT + 7) / 8, 256, 0, stream>>>(x, omega, offs, perm, down);
    gather_kernel<<<(N_IN + 3) / 4, 256, 0, stream>>>(
        delta, cand_mask, cand_idx, down, out);
}